// Round 2
// baseline (1470.205 us; speedup 1.0000x reference)
//
#include <hip/hip_runtime.h>
#include <hip/hip_bf16.h>
#include <stdint.h>

// frames: (B=4,S=8,N=2,C=4,H=480,W=640) f32 -> dense (32, 8ch, 480, 640)
// mask = max_c |dense[bf,c,y,x]| > 3.0 ; emit first 200000 survivors in
// (bf,y,x) row-major order. out = [features 200000x8][coords 200000x4].
#define HW        307200        // 480*640
#define W_IMG     640
#define TILE      1024          // pixels per block (256 thr x float4)
#define NTILES    9600          // 32*307200/1024
#define BLK_PER_BF 300          // HW/TILE (tiles never straddle a bf image)
#define MAXPTS    200000
#define COORD_OFF 1600000       // 200000*8 floats

// ws layout: [0,8) ticket (u32 used), [64, 64+NTILES*8) lookback statuses
// status word: high32 flag (0=invalid,1=aggregate,2=prefix), low32 value

__device__ __forceinline__ unsigned waveSum(unsigned v) {
#pragma unroll
    for (int off = 32; off >= 1; off >>= 1)
        v += __shfl_xor(v, off, 64);
    return v;
}

__device__ __forceinline__ float comp4(const float4& q, int i) {
    return i == 0 ? q.x : i == 1 ? q.y : i == 2 ? q.z : q.w;
}

__global__ __launch_bounds__(256) void fused_voxelizer(
        const float* __restrict__ frames, float* __restrict__ out,
        unsigned* __restrict__ ticket, unsigned long long* __restrict__ status) {
    __shared__ unsigned s_tile;
    __shared__ unsigned s_wsum[4];
    __shared__ unsigned s_prefix;

    int tid  = threadIdx.x;
    int lane = tid & 63, wave = tid >> 6;

    // dynamic tile assignment: ticket order == processing order -> no deadlock
    if (tid == 0) s_tile = atomicAdd(ticket, 1u);
    __syncthreads();
    unsigned tile = s_tile;

    int bf      = (int)(tile / BLK_PER_BF);
    int pixBase = (int)(tile - (unsigned)bf * BLK_PER_BF) * TILE + tid * 4;
    const float* base = frames + (size_t)bf * (8 * (size_t)HW) + pixBase;

    // 8 channels x float4 (4 consecutive pixels) = 128 B/thread, coalesced
    float4 v[8];
#pragma unroll
    for (int c = 0; c < 8; ++c)
        v[c] = *(const float4*)(base + (size_t)c * HW);

    float m0 = 0.f, m1 = 0.f, m2 = 0.f, m3 = 0.f;
#pragma unroll
    for (int c = 0; c < 8; ++c) {
        m0 = fmaxf(m0, fabsf(v[c].x));
        m1 = fmaxf(m1, fabsf(v[c].y));
        m2 = fmaxf(m2, fabsf(v[c].z));
        m3 = fmaxf(m3, fabsf(v[c].w));
    }
    int k0 = m0 > 3.0f, k1 = m1 > 3.0f, k2 = m2 > 3.0f, k3 = m3 > 3.0f;
    unsigned cnt = (unsigned)(k0 + k1 + k2 + k3);

    // wave-inclusive scan of per-thread counts (thread order == pixel order)
    unsigned inc = cnt;
#pragma unroll
    for (int off = 1; off < 64; off <<= 1) {
        unsigned n = __shfl_up(inc, off, 64);
        if (lane >= off) inc += n;
    }
    if (lane == 63) s_wsum[wave] = inc;
    __syncthreads();
    unsigned wbase = 0;
#pragma unroll
    for (int w = 0; w < 4; ++w)
        if (w < wave) wbase += s_wsum[w];
    unsigned total = s_wsum[0] + s_wsum[1] + s_wsum[2] + s_wsum[3];
    unsigned excl  = wbase + inc - cnt;   // block-local exclusive prefix

    // decoupled lookback, 64-wide window, wave 0 only
    if (wave == 0) {
        if (lane == 0)
            __hip_atomic_store(&status[tile],
                               (1ull << 32) | (unsigned long long)total,
                               __ATOMIC_RELEASE, __HIP_MEMORY_SCOPE_AGENT);
        unsigned pfx = 0;
        int end = (int)tile;                  // window covers [end-64, end)
        while (end > 0) {
            int idx = end - 64 + lane;
            bool have = idx >= 0;
            unsigned long long s = 0;
            while (true) {
                if (have && (s >> 32) == 0)
                    s = __hip_atomic_load(&status[idx], __ATOMIC_ACQUIRE,
                                          __HIP_MEMORY_SCOPE_AGENT);
                bool ok = !have || (s >> 32) != 0;
                if (__ballot(ok) == ~0ull) break;
                __builtin_amdgcn_s_sleep(1);
            }
            unsigned long long pmask = __ballot(have && (s >> 32) == 2);
            if (pmask) {
                int lp = 63 - __clzll(pmask); // highest lane holding a PREFIX
                unsigned contrib = (have && lane >= lp) ? (unsigned)s : 0;
                pfx += waveSum(contrib);
                break;
            } else {
                unsigned contrib = have ? (unsigned)s : 0;
                pfx += waveSum(contrib);
                end -= 64;
            }
        }
        if (lane == 0) {
            __hip_atomic_store(&status[tile],
                               (2ull << 32) | (unsigned long long)(pfx + total),
                               __ATOMIC_RELEASE, __HIP_MEMORY_SCOPE_AGENT);
            s_prefix = pfx;
        }
    }
    __syncthreads();
    unsigned r = s_prefix + excl;

    int k[4] = {k0, k1, k2, k3};
#pragma unroll
    for (int i = 0; i < 4; ++i) {
        if (k[i]) {
            if (r < MAXPTS) {
                float f0 = comp4(v[0], i), f1 = comp4(v[1], i);
                float f2 = comp4(v[2], i), f3 = comp4(v[3], i);
                float f4 = comp4(v[4], i), f5 = comp4(v[5], i);
                float f6 = comp4(v[6], i), f7 = comp4(v[7], i);
                float4* fo = (float4*)(out + (size_t)r * 8);
                fo[0] = make_float4(f0, f1, f2, f3);
                fo[1] = make_float4(f4, f5, f6, f7);
                int pix = pixBase + i;            // offset within this bf image
                int y = pix / W_IMG;
                int x = pix - y * W_IMG;
                float4* co = (float4*)(out + COORD_OFF) + r;
                *co = make_float4((float)(bf >> 3), (float)(bf & 7),
                                  (float)y, (float)x);
            }
            r++;
        }
    }
}

extern "C" void kernel_launch(void* const* d_in, const int* in_sizes, int n_in,
                              void* d_out, int out_size, void* d_ws, size_t ws_size,
                              hipStream_t stream) {
    const float* frames = (const float*)d_in[0];
    float* out = (float*)d_out;

    char* ws = (char*)d_ws;
    unsigned* ticket = (unsigned*)ws;
    unsigned long long* status = (unsigned long long*)(ws + 64);

    // ws is poisoned 0xAA before every call: zero ticket + statuses
    hipMemsetAsync(d_ws, 0, 64 + (size_t)NTILES * 8, stream);
    // rows >= n_valid must read 0
    hipMemsetAsync(d_out, 0, (size_t)out_size * sizeof(float), stream);

    fused_voxelizer<<<NTILES, 256, 0, stream>>>(frames, out, ticket, status);
}

// Round 3
// 437.988 us; speedup vs baseline: 3.3567x; 3.3567x over previous
//
#include <hip/hip_runtime.h>
#include <hip/hip_bf16.h>
#include <stdint.h>

// frames: (B=4,S=8,N=2,C=4,H=480,W=640) f32 -> dense (32, 8ch, 480, 640)
// mask = max_c |dense[bf,c,y,x]| > 3.0 ; emit first 200000 survivors in
// (bf,y,x) row-major order. out = [features 200000x8][coords 200000x4].
#define HW        307200        // 480*640
#define W_IMG     640
#define TILE      1024          // pixels per block (256 thr x float4)
#define NTILES    9600          // 32*307200/1024
#define BLK_PER_BF 300          // HW/TILE (tiles never straddle a bf image)
#define MAXPTS    200000
#define COORD_OFF 1600000       // 200000*8 floats

// ws layout:
//   [0)       u32 counts[NTILES]                      38,400 B
//   [65536)   u32 offsets[NTILES]                     38,400 B
//   [131072)  f32 data[NTILES][TILE][12]         471,859,200 B  (feat8+coord4)
#define WS_OFFSETS 65536
#define WS_DATA    131072

__device__ __forceinline__ float comp4(const float4& q, int i) {
    return i == 0 ? q.x : i == 1 ? q.y : i == 2 ? q.z : q.w;
}

__global__ __launch_bounds__(256) void compact_kernel(
        const float* __restrict__ frames, unsigned* __restrict__ counts,
        float* __restrict__ data) {
    __shared__ unsigned s_wsum[4];

    int tid  = threadIdx.x;
    int lane = tid & 63, wave = tid >> 6;
    int tile = blockIdx.x;

    int bf      = tile / BLK_PER_BF;
    int pixBase = (tile - bf * BLK_PER_BF) * TILE + tid * 4;
    const float* base = frames + (size_t)bf * (8 * (size_t)HW) + pixBase;

    // 8 channels x float4 (4 consecutive pixels) = 128 B/thread, coalesced
    float4 v[8];
#pragma unroll
    for (int c = 0; c < 8; ++c)
        v[c] = *(const float4*)(base + (size_t)c * HW);

    float m0 = 0.f, m1 = 0.f, m2 = 0.f, m3 = 0.f;
#pragma unroll
    for (int c = 0; c < 8; ++c) {
        m0 = fmaxf(m0, fabsf(v[c].x));
        m1 = fmaxf(m1, fabsf(v[c].y));
        m2 = fmaxf(m2, fabsf(v[c].z));
        m3 = fmaxf(m3, fabsf(v[c].w));
    }
    int k0 = m0 > 3.0f, k1 = m1 > 3.0f, k2 = m2 > 3.0f, k3 = m3 > 3.0f;
    unsigned cnt = (unsigned)(k0 + k1 + k2 + k3);

    // wave-inclusive scan of per-thread counts (thread order == pixel order)
    unsigned inc = cnt;
#pragma unroll
    for (int off = 1; off < 64; off <<= 1) {
        unsigned n = __shfl_up(inc, off, 64);
        if (lane >= off) inc += n;
    }
    if (lane == 63) s_wsum[wave] = inc;
    __syncthreads();
    unsigned wbase = 0;
#pragma unroll
    for (int w = 0; w < 4; ++w)
        if (w < wave) wbase += s_wsum[w];
    unsigned excl = wbase + inc - cnt;    // block-local exclusive prefix

    if (tid == 255) counts[tile] = excl + cnt;   // block total

    // write survivors compacted within this tile's slot (coalesced: local
    // ranks are dense in thread order)
    float* tbase = data + (size_t)tile * (TILE * 12);
    unsigned r = excl;
    int k[4] = {k0, k1, k2, k3};
#pragma unroll
    for (int i = 0; i < 4; ++i) {
        if (k[i]) {
            float4* p = (float4*)(tbase + (size_t)r * 12);
            p[0] = make_float4(comp4(v[0], i), comp4(v[1], i),
                               comp4(v[2], i), comp4(v[3], i));
            p[1] = make_float4(comp4(v[4], i), comp4(v[5], i),
                               comp4(v[6], i), comp4(v[7], i));
            int pix = pixBase + i;           // offset within this bf image
            int y = pix / W_IMG;
            int x = pix - y * W_IMG;
            p[2] = make_float4((float)(bf >> 3), (float)(bf & 7),
                               (float)y, (float)x);
            r++;
        }
    }
}

__global__ __launch_bounds__(256) void scan_kernel(const unsigned* __restrict__ counts,
                                                   unsigned* __restrict__ offsets) {
    __shared__ unsigned s[256];
    int tid = threadIdx.x;
    const int per = (NTILES + 255) / 256;  // 38
    int begin = tid * per;
    int end   = begin + per > NTILES ? NTILES : begin + per;
    unsigned sum = 0;
    for (int i = begin; i < end; ++i) sum += counts[i];
    s[tid] = sum;
    __syncthreads();
    if (tid == 0) {
        unsigned acc = 0;
        for (int i = 0; i < 256; ++i) { unsigned v = s[i]; s[i] = acc; acc += v; }
    }
    __syncthreads();
    unsigned acc = s[tid];
    for (int i = begin; i < end; ++i) { offsets[i] = acc; acc += counts[i]; }
}

__global__ __launch_bounds__(256) void scatter_kernel(
        const float* __restrict__ data, const unsigned* __restrict__ counts,
        const unsigned* __restrict__ offsets, float* __restrict__ out) {
    int tile = blockIdx.x;
    unsigned g = offsets[tile];
    unsigned c = counts[tile];
    const float* tbase = data + (size_t)tile * (TILE * 12);
    for (unsigned j = threadIdx.x; j < c; j += 256) {
        unsigned r = g + j;
        if (r >= MAXPTS) break;
        const float4* p = (const float4*)(tbase + (size_t)j * 12);
        float4 f0 = p[0], f1 = p[1], co = p[2];
        float4* fo = (float4*)(out + (size_t)r * 8);
        fo[0] = f0;
        fo[1] = f1;
        ((float4*)(out + COORD_OFF))[r] = co;
    }
}

extern "C" void kernel_launch(void* const* d_in, const int* in_sizes, int n_in,
                              void* d_out, int out_size, void* d_ws, size_t ws_size,
                              hipStream_t stream) {
    const float* frames = (const float*)d_in[0];
    float* out = (float*)d_out;

    char* ws = (char*)d_ws;
    unsigned* counts  = (unsigned*)ws;
    unsigned* offsets = (unsigned*)(ws + WS_OFFSETS);
    float*    data    = (float*)(ws + WS_DATA);

    // rows >= n_valid must read 0 (harness poisons d_out each call)
    hipMemsetAsync(d_out, 0, (size_t)out_size * sizeof(float), stream);

    compact_kernel<<<NTILES, 256, 0, stream>>>(frames, counts, data);
    scan_kernel<<<1, 256, 0, stream>>>(counts, offsets);
    scatter_kernel<<<NTILES, 256, 0, stream>>>(data, counts, offsets, out);
}